// Round 4
// baseline (267.585 us; speedup 1.0000x reference)
//
#include <hip/hip_runtime.h>

#define DIM  33
#define DIM2 1089      // 33*33
#define DIM3 35937     // 33*33*33
#define HW   2073600   // 1080*1920
#define HW8  259200    // HW/8
#define NPIX 8294400   // 4*HW

// Native vector types (HIP float4 is a class; builtins & clean codegen want these)
typedef float        vf4 __attribute__((ext_vector_type(4)));
typedef unsigned int vu4 __attribute__((ext_vector_type(4)));
typedef unsigned int vu2 __attribute__((ext_vector_type(2)));

// ws layout: [0..63]: float scale info (sc[0]=s, sc[1]=127/max), [256...]: u8 table
#define TBL_OFF 256          // bytes; keeps table 64B-aligned
#define ENTRY_DW 8           // 32B per lattice cell (24B used: 8 corners x 3ch u8)

// ---------------------------------------------------------------------------
// Kernel 1: one-workgroup max|LUT| reduction -> s = max/127, inv = 127/max.
// ---------------------------------------------------------------------------
__global__ __launch_bounds__(1024) void lut_maxabs_kernel(
        const float* __restrict__ lut, float* __restrict__ sc) {
    __shared__ float red[1024];
    float m = 0.0f;
    for (int i = threadIdx.x; i < 3 * DIM3; i += 1024)
        m = fmaxf(m, fabsf(lut[i]));
    red[threadIdx.x] = m;
    __syncthreads();
    for (int s = 512; s > 0; s >>= 1) {
        if ((int)threadIdx.x < s)
            red[threadIdx.x] = fmaxf(red[threadIdx.x], red[threadIdx.x + s]);
        __syncthreads();
    }
    if (threadIdx.x == 0) {
        float mx = fmaxf(red[0], 1e-20f);
        sc[0] = mx / 127.0f;     // s
        sc[1] = 127.0f / mx;     // 1/s
    }
}

// ---------------------------------------------------------------------------
// Kernel 2: expand+quantize LUT -> per-cell 32B entry.
// byte k = corner*3 + ch, corner = ((db*2+dg)*2+dr). u8 = round(v/s) + 128.
// ---------------------------------------------------------------------------
__global__ __launch_bounds__(256) void pack_lut_u8_kernel(
        const float* __restrict__ lut, const float* __restrict__ sc,
        unsigned int* __restrict__ tbl) {
    int i = blockIdx.x * blockDim.x + threadIdx.x;
    if (i >= DIM3) return;
    float inv = sc[1];
    int b   = i / DIM2;
    int rem = i - b * DIM2;
    int g   = rem / DIM;
    int r   = rem - g * DIM;
    int b1 = min(b + 1, DIM - 1);
    int g1 = min(g + 1, DIM - 1);
    int r1 = min(r + 1, DIM - 1);

    unsigned char u[24];
#pragma unroll
    for (int db = 0; db < 2; ++db)
#pragma unroll
        for (int dg = 0; dg < 2; ++dg)
#pragma unroll
            for (int dr = 0; dr < 2; ++dr) {
                int bb = db ? b1 : b;
                int gg = dg ? g1 : g;
                int rr = dr ? r1 : r;
                int base = bb * DIM2 + gg * DIM + rr;
                int ci = ((db * 2 + dg) * 2 + dr) * 3;
#pragma unroll
                for (int c = 0; c < 3; ++c) {
                    float v = lut[base + c * DIM3];
                    int q = __float2int_rn(v * inv) + 128;
                    q = min(max(q, 0), 255);
                    u[ci + c] = (unsigned char)q;
                }
            }
    unsigned int d[6];
#pragma unroll
    for (int w = 0; w < 6; ++w)
        d[w] = (unsigned)u[4 * w] | ((unsigned)u[4 * w + 1] << 8) |
               ((unsigned)u[4 * w + 2] << 16) | ((unsigned)u[4 * w + 3] << 24);
    unsigned int* e = tbl + (size_t)i * ENTRY_DW;
    *(vu4*)e       = (vu4){d[0], d[1], d[2], d[3]};
    *(vu4*)(e + 4) = (vu4){d[4], d[5], 0u, 0u};
}

__device__ __forceinline__ float ub(unsigned v, int b) {
    return (float)((v >> (8 * b)) & 0xffu);   // -> v_cvt_f32_ubyteN
}

// ---------------------------------------------------------------------------
// Main kernel: 8 pixels/thread. Phase 1 issues all 16 gathers (dwordx4+dwordx2
// per pixel, one 64B line each); phase 2 does the unpack + trilerp math.
// ---------------------------------------------------------------------------
__global__ __launch_bounds__(256) void lut_apply_u8(
        const float* __restrict__ x, const unsigned int* __restrict__ tbl,
        const float* __restrict__ sc, float* __restrict__ out) {
    int t = blockIdx.x * blockDim.x + threadIdx.x;
    if (t >= NPIX / 8) return;
    int n   = t / HW8;
    int rem = t - n * HW8;
    size_t base = (size_t)n * (size_t)(3 * HW) + (size_t)rem * 8;

    const vf4 r0 = __builtin_nontemporal_load((const vf4*)(x + base));
    const vf4 r1 = __builtin_nontemporal_load((const vf4*)(x + base + 4));
    const vf4 g0 = __builtin_nontemporal_load((const vf4*)(x + base + HW));
    const vf4 g1 = __builtin_nontemporal_load((const vf4*)(x + base + HW + 4));
    const vf4 b0 = __builtin_nontemporal_load((const vf4*)(x + base + 2 * (size_t)HW));
    const vf4 b1 = __builtin_nontemporal_load((const vf4*)(x + base + 2 * (size_t)HW + 4));

    float fr[8], fg[8], fb[8];
    vu4 q0[8];
    vu2 q1[8];
#pragma unroll
    for (int k = 0; k < 8; ++k) {
        float rc = (k < 4) ? r0[k & 3] : r1[k & 3];
        float gc = (k < 4) ? g0[k & 3] : g1[k & 3];
        float bc = (k < 4) ? b0[k & 3] : b1[k & 3];
        float rs = fminf(fmaxf(rc, 0.0f), 1.0f) * 32.0f;
        float gs = fminf(fmaxf(gc, 0.0f), 1.0f) * 32.0f;
        float bs = fminf(fmaxf(bc, 0.0f), 1.0f) * 32.0f;
        int ri = min((int)rs, 31);   // rs >= 0 so (int) == floor
        int gi = min((int)gs, 31);
        int bi = min((int)bs, 31);
        fr[k] = rs - (float)ri;
        fg[k] = gs - (float)gi;
        fb[k] = bs - (float)bi;
        const unsigned int* e = tbl + (size_t)(bi * DIM2 + gi * DIM + ri) * ENTRY_DW;
        q0[k] = *(const vu4*)e;        // bytes 0..15  (corners 0..4 + part 5)
        q1[k] = *(const vu2*)(e + 4);  // bytes 16..23 (rest)
    }

    const float s_   = sc[0];
    const float bias = -128.0f * s_;
    float oa[8], ob[8], oc[8];
#pragma unroll
    for (int k = 0; k < 8; ++k) {
        unsigned d[6] = {q0[k][0], q0[k][1], q0[k][2], q0[k][3], q1[k][0], q1[k][1]};
        float wr1 = fr[k], wr0 = 1.0f - wr1;
        float wg1 = fg[k], wg0 = 1.0f - wg1;
        float wb1 = fb[k], wb0 = 1.0f - wb1;
        float w[8];
        w[0] = wb0 * wg0 * wr0;  // (db,dg,dr)=(0,0,0)
        w[1] = wb0 * wg0 * wr1;
        w[2] = wb0 * wg1 * wr0;
        w[3] = wb0 * wg1 * wr1;
        w[4] = wb1 * wg0 * wr0;
        w[5] = wb1 * wg0 * wr1;
        w[6] = wb1 * wg1 * wr0;
        w[7] = wb1 * wg1 * wr1;
        float a0 = 0.0f, a1 = 0.0f, a2 = 0.0f;
#pragma unroll
        for (int c = 0; c < 8; ++c) {
            int i0 = c * 3, i1 = c * 3 + 1, i2 = c * 3 + 2;
            a0 = fmaf(w[c], ub(d[i0 >> 2], i0 & 3), a0);
            a1 = fmaf(w[c], ub(d[i1 >> 2], i1 & 3), a1);
            a2 = fmaf(w[c], ub(d[i2 >> 2], i2 & 3), a2);
        }
        oa[k] = fmaf(s_, a0, bias);
        ob[k] = fmaf(s_, a1, bias);
        oc[k] = fmaf(s_, a2, bias);
    }

    vf4 s0 = {oa[0], oa[1], oa[2], oa[3]};
    vf4 s1 = {oa[4], oa[5], oa[6], oa[7]};
    vf4 s2 = {ob[0], ob[1], ob[2], ob[3]};
    vf4 s3 = {ob[4], ob[5], ob[6], ob[7]};
    vf4 s4 = {oc[0], oc[1], oc[2], oc[3]};
    vf4 s5 = {oc[4], oc[5], oc[6], oc[7]};
    __builtin_nontemporal_store(s0, (vf4*)(out + base));
    __builtin_nontemporal_store(s1, (vf4*)(out + base + 4));
    __builtin_nontemporal_store(s2, (vf4*)(out + base + HW));
    __builtin_nontemporal_store(s3, (vf4*)(out + base + HW + 4));
    __builtin_nontemporal_store(s4, (vf4*)(out + base + 2 * (size_t)HW));
    __builtin_nontemporal_store(s5, (vf4*)(out + base + 2 * (size_t)HW + 4));
}

extern "C" void kernel_launch(void* const* d_in, const int* in_sizes, int n_in,
                              void* d_out, int out_size, void* d_ws, size_t ws_size,
                              hipStream_t stream) {
    const float* x   = (const float*)d_in[0];
    const float* lut = (const float*)d_in[1];
    float* out = (float*)d_out;

    float*        sc  = (float*)d_ws;
    unsigned int* tbl = (unsigned int*)((char*)d_ws + TBL_OFF);

    lut_maxabs_kernel<<<1, 1024, 0, stream>>>(lut, sc);
    pack_lut_u8_kernel<<<(DIM3 + 255) / 256, 256, 0, stream>>>(lut, sc, tbl);

    const int threads = NPIX / 8;                 // 1,036,800
    lut_apply_u8<<<(threads + 255) / 256, 256, 0, stream>>>(x, tbl, sc, out);
}

// Round 5
// 201.842 us; speedup vs baseline: 1.3257x; 1.3257x over previous
//
#include <hip/hip_runtime.h>

#define DIM  33
#define DIM2 1089      // 33*33
#define DIM3 35937     // 33*33*33
#define HW   2073600   // 1080*1920
#define HW4  518400    // HW/4
#define NPIX 8294400   // 4*HW
#define GROUPS (NPIX / 4)                     // 2,073,600 float4 pixel-groups
#define CHUNK  4096                           // groups per dynamically-claimed chunk
#define NCHUNK ((GROUPS + CHUNK - 1) / CHUNK) // 507
#define LDS_BYTES (DIM3 * 4)                  // 143,748 B — needs the 160KB attr
#define MAIN_BLOCKS  256
#define MAIN_THREADS 1024

// Native vector type — HIP's float4 is a class, rejected by nontemporal builtins.
typedef float vf4 __attribute__((ext_vector_type(4)));

// ws layout: u32[0] = chunk counter, u32[1] = max|LUT| bits; table at byte 64.
#define TBL_OFF 64

__device__ __forceinline__ float ub(unsigned v, int b) {
    return (float)((v >> (8 * b)) & 0xffu);   // -> v_cvt_f32_ubyteN
}

// ---------------------------------------------------------------------------
// Kernel 1: parallel max|LUT| -> maxbits (float bits as uint; all >=0 so
// uint atomicMax is order-preserving). One atomic per wave.
// ---------------------------------------------------------------------------
__global__ __launch_bounds__(256) void lut_maxabs_kernel(
        const float* __restrict__ lut, unsigned* __restrict__ maxbits) {
    int i = blockIdx.x * 256 + threadIdx.x;
    float m = 0.0f;
    if (i < 3 * DIM3) m = fabsf(lut[i]);
#pragma unroll
    for (int off = 32; off > 0; off >>= 1)
        m = fmaxf(m, __shfl_down(m, off, 64));
    if ((threadIdx.x & 63) == 0)
        atomicMax(maxbits, __float_as_uint(m));
}

// ---------------------------------------------------------------------------
// Kernel 2: quantize LUT to u8 with global scale s = max/127, biased +128.
// tbl[i] = r | g<<8 | b<<16 for lattice cell i (layout [b][g][r]).
// All loads/stores fully coalesced (3 planar streams, stride DIM3).
// ---------------------------------------------------------------------------
__global__ __launch_bounds__(256) void pack_lut_u8_kernel(
        const float* __restrict__ lut, const unsigned* __restrict__ maxbits,
        unsigned* __restrict__ tbl) {
    int i = blockIdx.x * 256 + threadIdx.x;
    if (i >= DIM3) return;
    float mx  = fmaxf(__uint_as_float(*maxbits), 1e-20f);
    float inv = 127.0f / mx;
    int q0 = min(max(__float2int_rn(lut[i]            * inv) + 128, 0), 255);
    int q1 = min(max(__float2int_rn(lut[i + DIM3]     * inv) + 128, 0), 255);
    int q2 = min(max(__float2int_rn(lut[i + 2 * DIM3] * inv) + 128, 0), 255);
    tbl[i] = (unsigned)q0 | ((unsigned)q1 << 8) | ((unsigned)q2 << 16);
}

// ---------------------------------------------------------------------------
// Kernel 3 (main): whole u8 LUT in LDS; persistent blocks, 1/CU (143.7KB LDS),
// dynamic chunk claiming so CU placement imbalance can't serialize.
// 4 px/thread keeps x-loads / out-stores perfectly lane-coalesced (16B stride).
// ---------------------------------------------------------------------------
extern __shared__ unsigned s_tbl[];

__global__ __launch_bounds__(MAIN_THREADS, 1) void lut_apply_lds(
        const float* __restrict__ x, const unsigned* __restrict__ tbl,
        unsigned* __restrict__ ctr, const unsigned* __restrict__ maxbits,
        float* __restrict__ out) {
    __shared__ unsigned chunk_s;
    // Stage the whole table into LDS (coalesced, ~35 iters/thread).
    for (int i = threadIdx.x; i < DIM3; i += MAIN_THREADS)
        s_tbl[i] = tbl[i];
    __syncthreads();

    const float mx   = fmaxf(__uint_as_float(*maxbits), 1e-20f);
    const float s_   = mx * (1.0f / 127.0f);
    const float bias = -128.0f * s_;

    for (;;) {
        if (threadIdx.x == 0) chunk_s = atomicAdd(ctr, 1u);
        __syncthreads();
        unsigned c = chunk_s;
        __syncthreads();              // all threads read c before next overwrite
        if (c >= NCHUNK) return;

        int gend = min((int)((c + 1) * CHUNK), GROUPS);
        for (int g = (int)(c * CHUNK) + threadIdx.x; g < gend; g += MAIN_THREADS) {
            int n   = g / HW4;
            int rem = g - n * HW4;
            size_t base = (size_t)n * (size_t)(3 * HW) + (size_t)rem * 4;

            const vf4 rv = __builtin_nontemporal_load((const vf4*)(x + base));
            const vf4 gv = __builtin_nontemporal_load((const vf4*)(x + base + HW));
            const vf4 bv = __builtin_nontemporal_load((const vf4*)(x + base + 2 * (size_t)HW));

            float oa[4], ob[4], oc[4];
#pragma unroll
            for (int k = 0; k < 4; ++k) {
                float rs = fminf(fmaxf(rv[k], 0.0f), 1.0f) * 32.0f;
                float gs = fminf(fmaxf(gv[k], 0.0f), 1.0f) * 32.0f;
                float bs = fminf(fmaxf(bv[k], 0.0f), 1.0f) * 32.0f;
                int ri = min((int)rs, 31);   // rs >= 0 so (int) == floor
                int gi = min((int)gs, 31);
                int bi = min((int)bs, 31);
                float fr = rs - (float)ri;
                float fg = gs - (float)gi;
                float fb = bs - (float)bi;

                int i00 = bi * DIM2 + gi * DIM + ri;
                // cXYZ: X=db (b), Y=dg (g), Z=dr (r)
                unsigned c000 = s_tbl[i00];
                unsigned c001 = s_tbl[i00 + 1];
                unsigned c010 = s_tbl[i00 + DIM];
                unsigned c011 = s_tbl[i00 + DIM + 1];
                unsigned c100 = s_tbl[i00 + DIM2];
                unsigned c101 = s_tbl[i00 + DIM2 + 1];
                unsigned c110 = s_tbl[i00 + DIM2 + DIM];
                unsigned c111 = s_tbl[i00 + DIM2 + DIM + 1];

                float wr1 = fr, wr0 = 1.0f - fr;
                float wg1 = fg, wg0 = 1.0f - fg;
                float wb1 = fb, wb0 = 1.0f - fb;
                float wb0g0 = wb0 * wg0, wb0g1 = wb0 * wg1;
                float wb1g0 = wb1 * wg0, wb1g1 = wb1 * wg1;
                float w000 = wb0g0 * wr0, w001 = wb0g0 * wr1;
                float w010 = wb0g1 * wr0, w011 = wb0g1 * wr1;
                float w100 = wb1g0 * wr0, w101 = wb1g0 * wr1;
                float w110 = wb1g1 * wr0, w111 = wb1g1 * wr1;

                float a0, a1, a2;
                a0 =      w000 * ub(c000, 0);
                a1 =      w000 * ub(c000, 1);
                a2 =      w000 * ub(c000, 2);
                a0 = fmaf(w001,  ub(c001, 0), a0);
                a1 = fmaf(w001,  ub(c001, 1), a1);
                a2 = fmaf(w001,  ub(c001, 2), a2);
                a0 = fmaf(w010,  ub(c010, 0), a0);
                a1 = fmaf(w010,  ub(c010, 1), a1);
                a2 = fmaf(w010,  ub(c010, 2), a2);
                a0 = fmaf(w011,  ub(c011, 0), a0);
                a1 = fmaf(w011,  ub(c011, 1), a1);
                a2 = fmaf(w011,  ub(c011, 2), a2);
                a0 = fmaf(w100,  ub(c100, 0), a0);
                a1 = fmaf(w100,  ub(c100, 1), a1);
                a2 = fmaf(w100,  ub(c100, 2), a2);
                a0 = fmaf(w101,  ub(c101, 0), a0);
                a1 = fmaf(w101,  ub(c101, 1), a1);
                a2 = fmaf(w101,  ub(c101, 2), a2);
                a0 = fmaf(w110,  ub(c110, 0), a0);
                a1 = fmaf(w110,  ub(c110, 1), a1);
                a2 = fmaf(w110,  ub(c110, 2), a2);
                a0 = fmaf(w111,  ub(c111, 0), a0);
                a1 = fmaf(w111,  ub(c111, 1), a1);
                a2 = fmaf(w111,  ub(c111, 2), a2);

                oa[k] = fmaf(s_, a0, bias);
                ob[k] = fmaf(s_, a1, bias);
                oc[k] = fmaf(s_, a2, bias);
            }
            vf4 s0 = {oa[0], oa[1], oa[2], oa[3]};
            vf4 s1 = {ob[0], ob[1], ob[2], ob[3]};
            vf4 s2 = {oc[0], oc[1], oc[2], oc[3]};
            __builtin_nontemporal_store(s0, (vf4*)(out + base));
            __builtin_nontemporal_store(s1, (vf4*)(out + base + HW));
            __builtin_nontemporal_store(s2, (vf4*)(out + base + 2 * (size_t)HW));
        }
    }
}

// ---------------------------------------------------------------------------
// Fallback path (if the 160KB dynamic-LDS attribute is rejected): round-3's
// verified fp16 64B-entry global-gather kernel (92.9 us main).
// ---------------------------------------------------------------------------
union F4H { vf4 f4; _Float16 h[8]; };

__global__ __launch_bounds__(256) void pack_lut8_kernel(
        const float* __restrict__ lut, vf4* __restrict__ lut8) {
    int i = blockIdx.x * blockDim.x + threadIdx.x;
    if (i >= DIM3) return;
    int b   = i / DIM2;
    int rem = i - b * DIM2;
    int g   = rem / DIM;
    int r   = rem - g * DIM;
    int b1 = min(b + 1, DIM - 1);
    int g1 = min(g + 1, DIM - 1);
    int r1 = min(r + 1, DIM - 1);
    _Float16 h[32];
#pragma unroll
    for (int db = 0; db < 2; ++db)
#pragma unroll
        for (int dg = 0; dg < 2; ++dg)
#pragma unroll
            for (int dr = 0; dr < 2; ++dr) {
                int bb = db ? b1 : b;
                int gg = dg ? g1 : g;
                int rr = dr ? r1 : r;
                int base = bb * DIM2 + gg * DIM + rr;
                int ci = ((db * 2 + dg) * 2 + dr) * 3;
                h[ci + 0] = (_Float16)lut[base];
                h[ci + 1] = (_Float16)lut[base + DIM3];
                h[ci + 2] = (_Float16)lut[base + 2 * DIM3];
            }
#pragma unroll
    for (int k = 24; k < 32; ++k) h[k] = (_Float16)0.0f;
    const vf4* hv = (const vf4*)h;
    vf4* dst = lut8 + (size_t)i * 4;
    dst[0] = hv[0]; dst[1] = hv[1]; dst[2] = hv[2]; dst[3] = hv[3];
}

__global__ __launch_bounds__(256) void lut_apply_fp16x8(
        const float* __restrict__ x, const vf4* __restrict__ lut8,
        float* __restrict__ out) {
    int i4 = blockIdx.x * blockDim.x + threadIdx.x;
    if (i4 >= NPIX / 4) return;
    int n   = i4 / HW4;
    int rem = i4 - n * HW4;
    size_t base = (size_t)n * (size_t)(3 * HW) + (size_t)rem * 4;
    const vf4 rv = __builtin_nontemporal_load((const vf4*)(x + base));
    const vf4 gv = __builtin_nontemporal_load((const vf4*)(x + base + HW));
    const vf4 bv = __builtin_nontemporal_load((const vf4*)(x + base + 2 * (size_t)HW));
    float oa[4], ob[4], oc[4];
#pragma unroll
    for (int k = 0; k < 4; ++k) {
        float rs = fminf(fmaxf(rv[k], 0.0f), 1.0f) * 32.0f;
        float gs = fminf(fmaxf(gv[k], 0.0f), 1.0f) * 32.0f;
        float bs = fminf(fmaxf(bv[k], 0.0f), 1.0f) * 32.0f;
        int ri = min((int)rs, 31);
        int gi = min((int)gs, 31);
        int bi = min((int)bs, 31);
        float fr = rs - (float)ri;
        float fg = gs - (float)gi;
        float fb = bs - (float)bi;
        const vf4* e = lut8 + (size_t)(bi * DIM2 + gi * DIM + ri) * 4;
        F4H q0, q1, q2;
        q0.f4 = e[0]; q1.f4 = e[1]; q2.f4 = e[2];
        float c[24];
#pragma unroll
        for (int j = 0; j < 8; ++j) {
            c[j] = (float)q0.h[j]; c[8 + j] = (float)q1.h[j]; c[16 + j] = (float)q2.h[j];
        }
        float wr[2] = {1.0f - fr, fr};
        float wg[2] = {1.0f - fg, fg};
        float wb[2] = {1.0f - fb, fb};
        float a0 = 0.0f, a1 = 0.0f, a2 = 0.0f;
#pragma unroll
        for (int db = 0; db < 2; ++db)
#pragma unroll
            for (int dg = 0; dg < 2; ++dg) {
                float wbg = wb[db] * wg[dg];
#pragma unroll
                for (int dr = 0; dr < 2; ++dr) {
                    float w = wbg * wr[dr];
                    int ci = ((db * 2 + dg) * 2 + dr) * 3;
                    a0 = fmaf(w, c[ci + 0], a0);
                    a1 = fmaf(w, c[ci + 1], a1);
                    a2 = fmaf(w, c[ci + 2], a2);
                }
            }
        oa[k] = a0; ob[k] = a1; oc[k] = a2;
    }
    vf4 s0 = {oa[0], oa[1], oa[2], oa[3]};
    vf4 s1 = {ob[0], ob[1], ob[2], ob[3]};
    vf4 s2 = {oc[0], oc[1], oc[2], oc[3]};
    __builtin_nontemporal_store(s0, (vf4*)(out + base));
    __builtin_nontemporal_store(s1, (vf4*)(out + base + HW));
    __builtin_nontemporal_store(s2, (vf4*)(out + base + 2 * (size_t)HW));
}

extern "C" void kernel_launch(void* const* d_in, const int* in_sizes, int n_in,
                              void* d_out, int out_size, void* d_ws, size_t ws_size,
                              hipStream_t stream) {
    const float* x   = (const float*)d_in[0];
    const float* lut = (const float*)d_in[1];
    float* out = (float*)d_out;

    unsigned* ctr     = (unsigned*)d_ws;                       // ws[0]
    unsigned* maxbits = (unsigned*)d_ws + 1;                   // ws[1]
    unsigned* tbl     = (unsigned*)((char*)d_ws + TBL_OFF);    // 143.7KB table

    // Raise the dynamic-LDS cap to 160KB for the main kernel (host-side,
    // capture-safe). Idempotent; done every call so behavior is uniform.
    static hipError_t attr_err = hipFuncSetAttribute(
        (const void*)lut_apply_lds,
        hipFuncAttributeMaxDynamicSharedMemorySize, LDS_BYTES);
    hipError_t err2 = hipFuncSetAttribute(
        (const void*)lut_apply_lds,
        hipFuncAttributeMaxDynamicSharedMemorySize, LDS_BYTES);

    if (attr_err == hipSuccess && err2 == hipSuccess) {
        hipMemsetAsync(d_ws, 0, 8, stream);   // zero ctr + maxbits
        lut_maxabs_kernel<<<(3 * DIM3 + 255) / 256, 256, 0, stream>>>(lut, maxbits);
        pack_lut_u8_kernel<<<(DIM3 + 255) / 256, 256, 0, stream>>>(lut, maxbits, tbl);
        lut_apply_lds<<<MAIN_BLOCKS, MAIN_THREADS, LDS_BYTES, stream>>>(
            x, tbl, ctr, maxbits, out);
    } else {
        vf4* lut8 = (vf4*)((char*)d_ws + TBL_OFF);             // 2.3MB fp16 table
        pack_lut8_kernel<<<(DIM3 + 255) / 256, 256, 0, stream>>>(lut, lut8);
        lut_apply_fp16x8<<<(GROUPS + 255) / 256, 256, 0, stream>>>(x, lut8, out);
    }
}